// Round 6
// baseline (629.078 us; speedup 1.0000x reference)
//
#include <hip/hip_runtime.h>

// SparseGrid trilinear interpolation (Plenoxels-style).
// reso = 128^3, data_dim = 28, npts = 2,000,000.
// Mapping: p = pt*64 + 63.5 (R=1, C=0, gsz=128 — exact in f32).
//
// Round-6: COUNTING-SORT BUCKETING by x-slab, then dense interp.
// R5's per-lane slab predication left every wave ~25% dense across 4x the
// waves. Now: K1 histogram -> K2 scan -> K3 scatter point-indices grouped
// by slab (8 slabs x 16 planes ~= 30 MB data each) into d_ws -> K4 interp
// over the permutation with 100% lane density. While slab s runs, its data
// slice is L3-resident -> data fetched from HBM ~once (224 MB) not 8x.

#define RES 128
#define DD  28     // 9*3+1 floats per row
#define NSLAB 8    // x-slabs of 16 planes each
#define PPB 64     // points per block (interp)
#define TPB (PPB * 7)

typedef float vf4 __attribute__((ext_vector_type(4)));

__device__ __forceinline__ int slab_of(float x) {
    float px = x * 64.0f + 63.5f;
    px = fminf(fmaxf(px, 0.0f), 127.0f);
    int lx = min((int)px, RES - 2);
    return lx >> 4;   // 16 planes per slab
}

// K1: per-slab histogram (block-local LDS, 8 global atomics per block)
__global__ __launch_bounds__(256) void count_kernel(
    const float* __restrict__ points, int npts, int* __restrict__ cnt)
{
    __shared__ int h[NSLAB];
    if (threadIdx.x < NSLAB) h[threadIdx.x] = 0;
    __syncthreads();
    int p = blockIdx.x * 256 + threadIdx.x;
    if (p < npts) atomicAdd(&h[slab_of(points[p * 3])], 1);
    __syncthreads();
    if (threadIdx.x < NSLAB) atomicAdd(&cnt[threadIdx.x], h[threadIdx.x]);
}

// K2: 8-wide exclusive scan -> cursor
__global__ void scan_kernel(const int* __restrict__ cnt, int* __restrict__ cursor)
{
    if (threadIdx.x == 0) {
        int acc = 0;
        for (int s = 0; s < NSLAB; ++s) { cursor[s] = acc; acc += cnt[s]; }
    }
}

// K3: scatter point indices grouped by slab
__global__ __launch_bounds__(256) void scatter_kernel(
    const float* __restrict__ points, int npts, int* __restrict__ cursor,
    int* __restrict__ idx)
{
    __shared__ int h[NSLAB];
    __shared__ int base[NSLAB];
    if (threadIdx.x < NSLAB) h[threadIdx.x] = 0;
    __syncthreads();
    int p = blockIdx.x * 256 + threadIdx.x;
    int s = 0, r = 0;
    if (p < npts) {
        s = slab_of(points[p * 3]);
        r = atomicAdd(&h[s], 1);          // rank within block
    }
    __syncthreads();
    if (threadIdx.x < NSLAB)
        base[threadIdx.x] = atomicAdd(&cursor[threadIdx.x], h[threadIdx.x]);
    __syncthreads();
    if (p < npts) idx[base[s] + r] = p;
}

// K4: dense interp over the slab-grouped permutation.
__global__ __launch_bounds__(TPB) void trilerp_kernel(
    const float* __restrict__ data,
    const float* __restrict__ points,
    const int*   __restrict__ links,
    const int*   __restrict__ idx,
    float*       __restrict__ out,
    int npts)
{
    const int tid  = threadIdx.x;
    const int j    = tid % 7;        // float4 chunk within the 28-float row
    const int pl   = tid / 7;        // local point index
    const int slot = blockIdx.x * PPB + pl;
    if (slot >= npts) return;
    const int p = idx[slot];

    float px = points[p * 3 + 0] * 64.0f + 63.5f;
    float py = points[p * 3 + 1] * 64.0f + 63.5f;
    float pz = points[p * 3 + 2] * 64.0f + 63.5f;

    px = fminf(fmaxf(px, 0.0f), 127.0f);
    py = fminf(fmaxf(py, 0.0f), 127.0f);
    pz = fminf(fmaxf(pz, 0.0f), 127.0f);

    int lx = min((int)px, RES - 2);
    int ly = min((int)py, RES - 2);
    int lz = min((int)pz, RES - 2);

    float wbx = px - (float)lx, wby = py - (float)ly, wbz = pz - (float)lz;
    float wax = 1.0f - wbx,     way = 1.0f - wby,     waz = 1.0f - wbz;

    const int base = (lx * RES + ly) * RES + lz;

    int ls[8];
    ls[0] = links[base];
    ls[1] = links[base + 1];
    ls[2] = links[base + RES];
    ls[3] = links[base + RES + 1];
    ls[4] = links[base + RES * RES];
    ls[5] = links[base + RES * RES + 1];
    ls[6] = links[base + RES * RES + RES];
    ls[7] = links[base + RES * RES + RES + 1];

    float w[8];
    w[0] = wax * way * waz;
    w[1] = wax * way * wbz;
    w[2] = wax * wby * waz;
    w[3] = wax * wby * wbz;
    w[4] = wbx * way * waz;
    w[5] = wbx * way * wbz;
    w[6] = wbx * wby * waz;
    w[7] = wbx * wby * wbz;

    vf4 v[8];
#pragma unroll
    for (int i = 0; i < 8; ++i) {
        const int li = ls[i] >= 0 ? ls[i] : 0;
        v[i] = *(const vf4*)(data + (long)li * DD + j * 4);
    }

    vf4 acc = (vf4)(0.0f);
#pragma unroll
    for (int i = 0; i < 8; ++i) {
        const float wi = ls[i] >= 0 ? w[i] : 0.0f;
        acc += wi * v[i];
    }

    vf4* o = (vf4*)(out + (long)p * DD + (long)j * 4);
    __builtin_nontemporal_store(acc, o);
}

// Fallback (no scratch): round-2 structure, direct order.
__global__ __launch_bounds__(TPB) void trilerp_direct_kernel(
    const float* __restrict__ data,
    const float* __restrict__ points,
    const int*   __restrict__ links,
    float*       __restrict__ out,
    int npts)
{
    const int tid = threadIdx.x;
    const int j   = tid % 7;
    const int pl  = tid / 7;
    const int p   = blockIdx.x * PPB + pl;
    if (p >= npts) return;

    float px = points[p * 3 + 0] * 64.0f + 63.5f;
    float py = points[p * 3 + 1] * 64.0f + 63.5f;
    float pz = points[p * 3 + 2] * 64.0f + 63.5f;
    px = fminf(fmaxf(px, 0.0f), 127.0f);
    py = fminf(fmaxf(py, 0.0f), 127.0f);
    pz = fminf(fmaxf(pz, 0.0f), 127.0f);
    int lx = min((int)px, RES - 2);
    int ly = min((int)py, RES - 2);
    int lz = min((int)pz, RES - 2);
    float wbx = px - (float)lx, wby = py - (float)ly, wbz = pz - (float)lz;
    float wax = 1.0f - wbx,     way = 1.0f - wby,     waz = 1.0f - wbz;
    const int base = (lx * RES + ly) * RES + lz;
    int ls[8];
    ls[0] = links[base];
    ls[1] = links[base + 1];
    ls[2] = links[base + RES];
    ls[3] = links[base + RES + 1];
    ls[4] = links[base + RES * RES];
    ls[5] = links[base + RES * RES + 1];
    ls[6] = links[base + RES * RES + RES];
    ls[7] = links[base + RES * RES + RES + 1];
    float w[8];
    w[0] = wax * way * waz; w[1] = wax * way * wbz;
    w[2] = wax * wby * waz; w[3] = wax * wby * wbz;
    w[4] = wbx * way * waz; w[5] = wbx * way * wbz;
    w[6] = wbx * wby * waz; w[7] = wbx * wby * wbz;
    vf4 v[8];
#pragma unroll
    for (int i = 0; i < 8; ++i) {
        const int li = ls[i] >= 0 ? ls[i] : 0;
        v[i] = *(const vf4*)(data + (long)li * DD + j * 4);
    }
    vf4 acc = (vf4)(0.0f);
#pragma unroll
    for (int i = 0; i < 8; ++i) {
        const float wi = ls[i] >= 0 ? w[i] : 0.0f;
        acc += wi * v[i];
    }
    vf4* o = (vf4*)(out + (long)p * DD + (long)j * 4);
    __builtin_nontemporal_store(acc, o);
}

extern "C" void kernel_launch(void* const* d_in, const int* in_sizes, int n_in,
                              void* d_out, int out_size, void* d_ws, size_t ws_size,
                              hipStream_t stream) {
    const float* data   = (const float*)d_in[0];
    const float* points = (const float*)d_in[1];
    const int*   links  = (const int*)d_in[2];
    float*       out    = (float*)d_out;

    int npts = in_sizes[1] / 3;

    const size_t need = (size_t)(2 * NSLAB + npts) * sizeof(int);
    if (ws_size < need) {
        const int grid = (npts + PPB - 1) / PPB;
        hipLaunchKernelGGL(trilerp_direct_kernel, dim3(grid), dim3(TPB), 0, stream,
                           data, points, links, out, npts);
        return;
    }

    int* cnt    = (int*)d_ws;          // [NSLAB]
    int* cursor = cnt + NSLAB;         // [NSLAB]
    int* idx    = cursor + NSLAB;      // [npts]

    hipMemsetAsync(cnt, 0, NSLAB * sizeof(int), stream);

    const int nb256 = (npts + 255) / 256;
    hipLaunchKernelGGL(count_kernel,   dim3(nb256), dim3(256), 0, stream, points, npts, cnt);
    hipLaunchKernelGGL(scan_kernel,    dim3(1),     dim3(64),  0, stream, cnt, cursor);
    hipLaunchKernelGGL(scatter_kernel, dim3(nb256), dim3(256), 0, stream, points, npts, cursor, idx);

    const int grid = (npts + PPB - 1) / PPB;
    hipLaunchKernelGGL(trilerp_kernel, dim3(grid), dim3(TPB), 0, stream,
                       data, points, links, idx, out, npts);
}

// Round 7
// 392.928 us; speedup vs baseline: 1.6010x; 1.6010x over previous
//
#include <hip/hip_runtime.h>

// SparseGrid trilinear interpolation (Plenoxels-style).
// reso = 128^3, data_dim = 28, npts = 2,000,000.
// Mapping: p = pt*64 + 63.5 (R=1, C=0, gsz=128 — exact in f32).
//
// Round-7: 3D BRICK BUCKETING (4096 buckets = 16^3 bricks of 8^3 cells)
// + packed point records.
// R6 lesson: x-slabs (28 MB) only helped ~15% — random order within a
// slab defeats per-XCD L2 (4 MB); and 8-address global-atomic cursors
// cost ~190 us. Now: brick halo = 9^3 rows * 112 B = 82 KB; the ~100+
// bucket in-flight window is ~10 MB (MALL-easy, ~1.4 MB per XCD L2), so
// each data row is fetched from HBM ~once and re-served from L2/MALL.
// Sort: LDS histograms, skip-zero merges over 4096 addresses (no
// hotspot), parallel scan, scatter writes 16 B records (x,y,z,p) so the
// interp kernel has no idx->points indirection.

#define RES 128
#define DD  28     // 9*3+1 floats per row
#define NBKT 4096  // 16^3 bricks
#define PPB 64     // points per block (interp)
#define TPB (PPB * 7)
#define SCAT_TPB 256
#define SCAT_PPT 8
#define SCAT_PTS (SCAT_TPB * SCAT_PPT)   // 2048 points per sort block

typedef float vf4 __attribute__((ext_vector_type(4)));

struct __align__(16) PtRec { float x, y, z; int p; };

__device__ __forceinline__ void cell_of(float x, float y, float z,
                                        int& lx, int& ly, int& lz) {
    float px = fminf(fmaxf(x * 64.0f + 63.5f, 0.0f), 127.0f);
    float py = fminf(fmaxf(y * 64.0f + 63.5f, 0.0f), 127.0f);
    float pz = fminf(fmaxf(z * 64.0f + 63.5f, 0.0f), 127.0f);
    lx = min((int)px, RES - 2);
    ly = min((int)py, RES - 2);
    lz = min((int)pz, RES - 2);
}

__device__ __forceinline__ int bucket_of(int lx, int ly, int lz) {
    return ((lx >> 3) << 8) | ((ly >> 3) << 4) | (lz >> 3);
}

// K1: per-bucket histogram. LDS hist, skip-zero global merge.
__global__ __launch_bounds__(SCAT_TPB) void count_kernel(
    const float* __restrict__ points, int npts, int* __restrict__ cnt)
{
    __shared__ int h[NBKT];
    for (int i = threadIdx.x; i < NBKT; i += SCAT_TPB) h[i] = 0;
    __syncthreads();
    const int p0 = blockIdx.x * SCAT_PTS;
#pragma unroll
    for (int k = 0; k < SCAT_PPT; ++k) {
        int p = p0 + k * SCAT_TPB + threadIdx.x;
        if (p < npts) {
            int lx, ly, lz;
            cell_of(points[p * 3], points[p * 3 + 1], points[p * 3 + 2], lx, ly, lz);
            atomicAdd(&h[bucket_of(lx, ly, lz)], 1);
        }
    }
    __syncthreads();
    for (int i = threadIdx.x; i < NBKT; i += SCAT_TPB)
        if (h[i]) atomicAdd(&cnt[i], h[i]);
}

// K2: exclusive scan of 4096 counts (1024 threads, 4 each, Hillis-Steele).
__global__ __launch_bounds__(1024) void scan_kernel(
    const int* __restrict__ cnt, int* __restrict__ cursor)
{
    __shared__ int part[1024];
    const int t = threadIdx.x;
    int a = cnt[4 * t], b = cnt[4 * t + 1], c = cnt[4 * t + 2], d = cnt[4 * t + 3];
    int sum = a + b + c + d;
    part[t] = sum;
    __syncthreads();
    for (int off = 1; off < 1024; off <<= 1) {
        int v = (t >= off) ? part[t - off] : 0;
        __syncthreads();
        part[t] += v;
        __syncthreads();
    }
    int excl = part[t] - sum;
    cursor[4 * t]     = excl;
    cursor[4 * t + 1] = excl + a;
    cursor[4 * t + 2] = excl + a + b;
    cursor[4 * t + 3] = excl + a + b + c;
}

// K3: scatter packed records grouped by bucket.
__global__ __launch_bounds__(SCAT_TPB) void scatter_kernel(
    const float* __restrict__ points, int npts, int* __restrict__ cursor,
    PtRec* __restrict__ recs)
{
    __shared__ int h[NBKT];
    __shared__ int base[NBKT];
    for (int i = threadIdx.x; i < NBKT; i += SCAT_TPB) h[i] = 0;
    __syncthreads();

    const int p0 = blockIdx.x * SCAT_PTS;
    float xs[SCAT_PPT], ys[SCAT_PPT], zs[SCAT_PPT];
    int   sb[SCAT_PPT], rk[SCAT_PPT];
#pragma unroll
    for (int k = 0; k < SCAT_PPT; ++k) {
        int p = p0 + k * SCAT_TPB + threadIdx.x;
        sb[k] = -1;
        if (p < npts) {
            xs[k] = points[p * 3];
            ys[k] = points[p * 3 + 1];
            zs[k] = points[p * 3 + 2];
            int lx, ly, lz;
            cell_of(xs[k], ys[k], zs[k], lx, ly, lz);
            sb[k] = bucket_of(lx, ly, lz);
            rk[k] = atomicAdd(&h[sb[k]], 1);
        }
    }
    __syncthreads();
    for (int i = threadIdx.x; i < NBKT; i += SCAT_TPB) {
        int c = h[i];
        base[i] = c ? atomicAdd(&cursor[i], c) : 0;
    }
    __syncthreads();
#pragma unroll
    for (int k = 0; k < SCAT_PPT; ++k) {
        if (sb[k] >= 0) {
            int p = p0 + k * SCAT_TPB + threadIdx.x;
            PtRec r; r.x = xs[k]; r.y = ys[k]; r.z = zs[k]; r.p = p;
            recs[base[sb[k]] + rk[k]] = r;
        }
    }
}

// K4: dense interp over bucket-grouped records.
__global__ __launch_bounds__(TPB) void trilerp_kernel(
    const float* __restrict__ data,
    const int*   __restrict__ links,
    const PtRec* __restrict__ recs,
    float*       __restrict__ out,
    int npts)
{
    const int tid  = threadIdx.x;
    const int j    = tid % 7;        // float4 chunk within the 28-float row
    const int pl   = tid / 7;        // local point index
    const int slot = blockIdx.x * PPB + pl;
    if (slot >= npts) return;
    const PtRec rec = recs[slot];
    const int p = rec.p;

    float px = rec.x * 64.0f + 63.5f;
    float py = rec.y * 64.0f + 63.5f;
    float pz = rec.z * 64.0f + 63.5f;

    px = fminf(fmaxf(px, 0.0f), 127.0f);
    py = fminf(fmaxf(py, 0.0f), 127.0f);
    pz = fminf(fmaxf(pz, 0.0f), 127.0f);

    int lx = min((int)px, RES - 2);
    int ly = min((int)py, RES - 2);
    int lz = min((int)pz, RES - 2);

    float wbx = px - (float)lx, wby = py - (float)ly, wbz = pz - (float)lz;
    float wax = 1.0f - wbx,     way = 1.0f - wby,     waz = 1.0f - wbz;

    const int base = (lx * RES + ly) * RES + lz;

    int ls[8];
    ls[0] = links[base];
    ls[1] = links[base + 1];
    ls[2] = links[base + RES];
    ls[3] = links[base + RES + 1];
    ls[4] = links[base + RES * RES];
    ls[5] = links[base + RES * RES + 1];
    ls[6] = links[base + RES * RES + RES];
    ls[7] = links[base + RES * RES + RES + 1];

    float w[8];
    w[0] = wax * way * waz;
    w[1] = wax * way * wbz;
    w[2] = wax * wby * waz;
    w[3] = wax * wby * wbz;
    w[4] = wbx * way * waz;
    w[5] = wbx * way * wbz;
    w[6] = wbx * wby * waz;
    w[7] = wbx * wby * wbz;

    vf4 v[8];
#pragma unroll
    for (int i = 0; i < 8; ++i) {
        const int li = ls[i] >= 0 ? ls[i] : 0;
        v[i] = *(const vf4*)(data + (long)li * DD + j * 4);
    }

    vf4 acc = (vf4)(0.0f);
#pragma unroll
    for (int i = 0; i < 8; ++i) {
        const float wi = ls[i] >= 0 ? w[i] : 0.0f;
        acc += wi * v[i];
    }

    vf4* o = (vf4*)(out + (long)p * DD + (long)j * 4);
    __builtin_nontemporal_store(acc, o);
}

// Fallback (no scratch): direct order.
__global__ __launch_bounds__(TPB) void trilerp_direct_kernel(
    const float* __restrict__ data,
    const float* __restrict__ points,
    const int*   __restrict__ links,
    float*       __restrict__ out,
    int npts)
{
    const int tid = threadIdx.x;
    const int j   = tid % 7;
    const int pl  = tid / 7;
    const int p   = blockIdx.x * PPB + pl;
    if (p >= npts) return;

    float px = points[p * 3 + 0] * 64.0f + 63.5f;
    float py = points[p * 3 + 1] * 64.0f + 63.5f;
    float pz = points[p * 3 + 2] * 64.0f + 63.5f;
    px = fminf(fmaxf(px, 0.0f), 127.0f);
    py = fminf(fmaxf(py, 0.0f), 127.0f);
    pz = fminf(fmaxf(pz, 0.0f), 127.0f);
    int lx = min((int)px, RES - 2);
    int ly = min((int)py, RES - 2);
    int lz = min((int)pz, RES - 2);
    float wbx = px - (float)lx, wby = py - (float)ly, wbz = pz - (float)lz;
    float wax = 1.0f - wbx,     way = 1.0f - wby,     waz = 1.0f - wbz;
    const int base = (lx * RES + ly) * RES + lz;
    int ls[8];
    ls[0] = links[base];
    ls[1] = links[base + 1];
    ls[2] = links[base + RES];
    ls[3] = links[base + RES + 1];
    ls[4] = links[base + RES * RES];
    ls[5] = links[base + RES * RES + 1];
    ls[6] = links[base + RES * RES + RES];
    ls[7] = links[base + RES * RES + RES + 1];
    float w[8];
    w[0] = wax * way * waz; w[1] = wax * way * wbz;
    w[2] = wax * wby * waz; w[3] = wax * wby * wbz;
    w[4] = wbx * way * waz; w[5] = wbx * way * wbz;
    w[6] = wbx * wby * waz; w[7] = wbx * wby * wbz;
    vf4 v[8];
#pragma unroll
    for (int i = 0; i < 8; ++i) {
        const int li = ls[i] >= 0 ? ls[i] : 0;
        v[i] = *(const vf4*)(data + (long)li * DD + j * 4);
    }
    vf4 acc = (vf4)(0.0f);
#pragma unroll
    for (int i = 0; i < 8; ++i) {
        const float wi = ls[i] >= 0 ? w[i] : 0.0f;
        acc += wi * v[i];
    }
    vf4* o = (vf4*)(out + (long)p * DD + (long)j * 4);
    __builtin_nontemporal_store(acc, o);
}

extern "C" void kernel_launch(void* const* d_in, const int* in_sizes, int n_in,
                              void* d_out, int out_size, void* d_ws, size_t ws_size,
                              hipStream_t stream) {
    const float* data   = (const float*)d_in[0];
    const float* points = (const float*)d_in[1];
    const int*   links  = (const int*)d_in[2];
    float*       out    = (float*)d_out;

    int npts = in_sizes[1] / 3;

    const size_t need = (size_t)2 * NBKT * sizeof(int) + (size_t)npts * sizeof(PtRec);
    if (ws_size < need) {
        const int grid = (npts + PPB - 1) / PPB;
        hipLaunchKernelGGL(trilerp_direct_kernel, dim3(grid), dim3(TPB), 0, stream,
                           data, points, links, out, npts);
        return;
    }

    int*   cnt    = (int*)d_ws;            // [NBKT]
    int*   cursor = cnt + NBKT;            // [NBKT]
    PtRec* recs   = (PtRec*)(cursor + NBKT);  // [npts], 16B-aligned (32KB offset)

    hipMemsetAsync(cnt, 0, NBKT * sizeof(int), stream);

    const int nbs = (npts + SCAT_PTS - 1) / SCAT_PTS;
    hipLaunchKernelGGL(count_kernel,   dim3(nbs), dim3(SCAT_TPB), 0, stream, points, npts, cnt);
    hipLaunchKernelGGL(scan_kernel,    dim3(1),   dim3(1024),     0, stream, cnt, cursor);
    hipLaunchKernelGGL(scatter_kernel, dim3(nbs), dim3(SCAT_TPB), 0, stream, points, npts, cursor, recs);

    const int grid = (npts + PPB - 1) / PPB;
    hipLaunchKernelGGL(trilerp_kernel, dim3(grid), dim3(TPB), 0, stream,
                       data, links, recs, out, npts);
}

// Round 8
// 319.314 us; speedup vs baseline: 1.9701x; 1.2305x over previous
//
#include <hip/hip_runtime.h>

// SparseGrid trilinear interpolation (Plenoxels-style).
// reso = 128^3, data_dim = 28, npts = 2,000,000.
// Mapping: p = pt*64 + 63.5 (R=1, C=0, gsz=128 — exact in f32).
//
// Round-8: 512 buckets (8^3 bricks of 16^3 cells) + XCD-chunked swizzle.
// R7 lessons: (a) 774 MB interp fetch — consecutive blocks of one bucket
// round-robin across 8 XCDs, so each XCD's L2 re-fetches the same brick
// halo; (b) sort ~110 us — 2M random 16 B record writes amplify ~8x, and
// 4096 buckets leave ~0.5 pts/bucket/block (no run-length).
// Fixes: 16^3 bricks (halo overlap 1.20x vs 1.42x; scatter runs ~4 recs;
// 2 KB LDS hists) and a bijective chunked blockIdx->XCD remap in interp
// so each XCD owns a contiguous slice of the sorted records (~1.4 MB
// active halo -> L2-resident per XCD).

#define RES 128
#define DD  28     // 9*3+1 floats per row
#define NBKT 512   // 8^3 bricks of 16^3 cells
#define PPB 64     // points per block (interp)
#define TPB (PPB * 7)

#define CNT_TPB 256
#define CNT_PPT 16
#define CNT_PTS (CNT_TPB * CNT_PPT)      // 4096 points per count block

#define SC_TPB 256
#define SC_PPT 8
#define SC_PTS (SC_TPB * SC_PPT)         // 2048 points per scatter block

typedef float vf4 __attribute__((ext_vector_type(4)));

struct __align__(16) PtRec { float x, y, z; int p; };

__device__ __forceinline__ void cell_of(float x, float y, float z,
                                        int& lx, int& ly, int& lz) {
    float px = fminf(fmaxf(x * 64.0f + 63.5f, 0.0f), 127.0f);
    float py = fminf(fmaxf(y * 64.0f + 63.5f, 0.0f), 127.0f);
    float pz = fminf(fmaxf(z * 64.0f + 63.5f, 0.0f), 127.0f);
    lx = min((int)px, RES - 2);
    ly = min((int)py, RES - 2);
    lz = min((int)pz, RES - 2);
}

__device__ __forceinline__ int bucket_of(int lx, int ly, int lz) {
    return ((lx >> 4) << 6) | ((ly >> 4) << 3) | (lz >> 4);
}

// K1: per-bucket histogram. LDS hist, skip-zero global merge.
__global__ __launch_bounds__(CNT_TPB) void count_kernel(
    const float* __restrict__ points, int npts, int* __restrict__ cnt)
{
    __shared__ int h[NBKT];
    for (int i = threadIdx.x; i < NBKT; i += CNT_TPB) h[i] = 0;
    __syncthreads();
    const int p0 = blockIdx.x * CNT_PTS;
#pragma unroll
    for (int k = 0; k < CNT_PPT; ++k) {
        int p = p0 + k * CNT_TPB + threadIdx.x;
        if (p < npts) {
            int lx, ly, lz;
            cell_of(points[p * 3], points[p * 3 + 1], points[p * 3 + 2], lx, ly, lz);
            atomicAdd(&h[bucket_of(lx, ly, lz)], 1);
        }
    }
    __syncthreads();
    for (int i = threadIdx.x; i < NBKT; i += CNT_TPB)
        if (h[i]) atomicAdd(&cnt[i], h[i]);
}

// K2: exclusive scan of 512 counts (single block, Hillis-Steele).
__global__ __launch_bounds__(NBKT) void scan_kernel(
    const int* __restrict__ cnt, int* __restrict__ cursor)
{
    __shared__ int part[NBKT];
    const int t = threadIdx.x;
    int v = cnt[t];
    part[t] = v;
    __syncthreads();
    for (int off = 1; off < NBKT; off <<= 1) {
        int u = (t >= off) ? part[t - off] : 0;
        __syncthreads();
        part[t] += u;
        __syncthreads();
    }
    cursor[t] = part[t] - v;   // exclusive
}

// K3: scatter packed records grouped by bucket.
__global__ __launch_bounds__(SC_TPB) void scatter_kernel(
    const float* __restrict__ points, int npts, int* __restrict__ cursor,
    PtRec* __restrict__ recs)
{
    __shared__ int h[NBKT];
    __shared__ int base[NBKT];
    for (int i = threadIdx.x; i < NBKT; i += SC_TPB) h[i] = 0;
    __syncthreads();

    const int p0 = blockIdx.x * SC_PTS;
    float xs[SC_PPT], ys[SC_PPT], zs[SC_PPT];
    int   sb[SC_PPT], rk[SC_PPT];
#pragma unroll
    for (int k = 0; k < SC_PPT; ++k) {
        int p = p0 + k * SC_TPB + threadIdx.x;
        sb[k] = -1;
        if (p < npts) {
            xs[k] = points[p * 3];
            ys[k] = points[p * 3 + 1];
            zs[k] = points[p * 3 + 2];
            int lx, ly, lz;
            cell_of(xs[k], ys[k], zs[k], lx, ly, lz);
            sb[k] = bucket_of(lx, ly, lz);
            rk[k] = atomicAdd(&h[sb[k]], 1);
        }
    }
    __syncthreads();
    for (int i = threadIdx.x; i < NBKT; i += SC_TPB) {
        int c = h[i];
        base[i] = c ? atomicAdd(&cursor[i], c) : 0;
    }
    __syncthreads();
#pragma unroll
    for (int k = 0; k < SC_PPT; ++k) {
        if (sb[k] >= 0) {
            int p = p0 + k * SC_TPB + threadIdx.x;
            PtRec r; r.x = xs[k]; r.y = ys[k]; r.z = zs[k]; r.p = p;
            recs[base[sb[k]] + rk[k]] = r;
        }
    }
}

// K4: dense interp over bucket-grouped records, XCD-chunked block order.
__global__ __launch_bounds__(TPB) void trilerp_kernel(
    const float* __restrict__ data,
    const int*   __restrict__ links,
    const PtRec* __restrict__ recs,
    float*       __restrict__ out,
    int npts)
{
    // Bijective chunked XCD remap (m204): HW round-robins blockIdx across
    // 8 XCDs; remap so XCD x processes a CONTIGUOUS chunk of the sorted
    // record array -> each XCD's 4 MB L2 holds its active brick halos.
    const int nwg  = gridDim.x;
    const int orig = blockIdx.x;
    const int q = nwg >> 3, r = nwg & 7;
    const int x = orig & 7, sl = orig >> 3;
    const int bid = (x < r) ? (x * (q + 1) + sl)
                            : (r * (q + 1) + (x - r) * q + sl);

    const int tid  = threadIdx.x;
    const int j    = tid % 7;        // float4 chunk within the 28-float row
    const int pl   = tid / 7;        // local point index
    const int slot = bid * PPB + pl;
    if (slot >= npts) return;
    const PtRec rec = recs[slot];
    const int p = rec.p;

    float px = rec.x * 64.0f + 63.5f;
    float py = rec.y * 64.0f + 63.5f;
    float pz = rec.z * 64.0f + 63.5f;

    px = fminf(fmaxf(px, 0.0f), 127.0f);
    py = fminf(fmaxf(py, 0.0f), 127.0f);
    pz = fminf(fmaxf(pz, 0.0f), 127.0f);

    int lx = min((int)px, RES - 2);
    int ly = min((int)py, RES - 2);
    int lz = min((int)pz, RES - 2);

    float wbx = px - (float)lx, wby = py - (float)ly, wbz = pz - (float)lz;
    float wax = 1.0f - wbx,     way = 1.0f - wby,     waz = 1.0f - wbz;

    const int base = (lx * RES + ly) * RES + lz;

    int ls[8];
    ls[0] = links[base];
    ls[1] = links[base + 1];
    ls[2] = links[base + RES];
    ls[3] = links[base + RES + 1];
    ls[4] = links[base + RES * RES];
    ls[5] = links[base + RES * RES + 1];
    ls[6] = links[base + RES * RES + RES];
    ls[7] = links[base + RES * RES + RES + 1];

    float w[8];
    w[0] = wax * way * waz;
    w[1] = wax * way * wbz;
    w[2] = wax * wby * waz;
    w[3] = wax * wby * wbz;
    w[4] = wbx * way * waz;
    w[5] = wbx * way * wbz;
    w[6] = wbx * wby * waz;
    w[7] = wbx * wby * wbz;

    vf4 v[8];
#pragma unroll
    for (int i = 0; i < 8; ++i) {
        const int li = ls[i] >= 0 ? ls[i] : 0;
        v[i] = *(const vf4*)(data + (long)li * DD + j * 4);
    }

    vf4 acc = (vf4)(0.0f);
#pragma unroll
    for (int i = 0; i < 8; ++i) {
        const float wi = ls[i] >= 0 ? w[i] : 0.0f;
        acc += wi * v[i];
    }

    vf4* o = (vf4*)(out + (long)p * DD + (long)j * 4);
    __builtin_nontemporal_store(acc, o);
}

// Fallback (no scratch): direct order.
__global__ __launch_bounds__(TPB) void trilerp_direct_kernel(
    const float* __restrict__ data,
    const float* __restrict__ points,
    const int*   __restrict__ links,
    float*       __restrict__ out,
    int npts)
{
    const int tid = threadIdx.x;
    const int j   = tid % 7;
    const int pl  = tid / 7;
    const int p   = blockIdx.x * PPB + pl;
    if (p >= npts) return;

    float px = points[p * 3 + 0] * 64.0f + 63.5f;
    float py = points[p * 3 + 1] * 64.0f + 63.5f;
    float pz = points[p * 3 + 2] * 64.0f + 63.5f;
    px = fminf(fmaxf(px, 0.0f), 127.0f);
    py = fminf(fmaxf(py, 0.0f), 127.0f);
    pz = fminf(fmaxf(pz, 0.0f), 127.0f);
    int lx = min((int)px, RES - 2);
    int ly = min((int)py, RES - 2);
    int lz = min((int)pz, RES - 2);
    float wbx = px - (float)lx, wby = py - (float)ly, wbz = pz - (float)lz;
    float wax = 1.0f - wbx,     way = 1.0f - wby,     waz = 1.0f - wbz;
    const int base = (lx * RES + ly) * RES + lz;
    int ls[8];
    ls[0] = links[base];
    ls[1] = links[base + 1];
    ls[2] = links[base + RES];
    ls[3] = links[base + RES + 1];
    ls[4] = links[base + RES * RES];
    ls[5] = links[base + RES * RES + 1];
    ls[6] = links[base + RES * RES + RES];
    ls[7] = links[base + RES * RES + RES + 1];
    float w[8];
    w[0] = wax * way * waz; w[1] = wax * way * wbz;
    w[2] = wax * wby * waz; w[3] = wax * wby * wbz;
    w[4] = wbx * way * waz; w[5] = wbx * way * wbz;
    w[6] = wbx * wby * waz; w[7] = wbx * wby * wbz;
    vf4 v[8];
#pragma unroll
    for (int i = 0; i < 8; ++i) {
        const int li = ls[i] >= 0 ? ls[i] : 0;
        v[i] = *(const vf4*)(data + (long)li * DD + j * 4);
    }
    vf4 acc = (vf4)(0.0f);
#pragma unroll
    for (int i = 0; i < 8; ++i) {
        const float wi = ls[i] >= 0 ? w[i] : 0.0f;
        acc += wi * v[i];
    }
    vf4* o = (vf4*)(out + (long)p * DD + (long)j * 4);
    __builtin_nontemporal_store(acc, o);
}

extern "C" void kernel_launch(void* const* d_in, const int* in_sizes, int n_in,
                              void* d_out, int out_size, void* d_ws, size_t ws_size,
                              hipStream_t stream) {
    const float* data   = (const float*)d_in[0];
    const float* points = (const float*)d_in[1];
    const int*   links  = (const int*)d_in[2];
    float*       out    = (float*)d_out;

    int npts = in_sizes[1] / 3;

    const size_t need = (size_t)2 * NBKT * sizeof(int) + 4096 + (size_t)npts * sizeof(PtRec);
    if (ws_size < need) {
        const int grid = (npts + PPB - 1) / PPB;
        hipLaunchKernelGGL(trilerp_direct_kernel, dim3(grid), dim3(TPB), 0, stream,
                           data, points, links, out, npts);
        return;
    }

    int*   cnt    = (int*)d_ws;                   // [NBKT]
    int*   cursor = cnt + NBKT;                   // [NBKT]
    PtRec* recs   = (PtRec*)((char*)d_ws + 2 * NBKT * sizeof(int) + 4096
                             - ((2 * NBKT * sizeof(int)) & 15));  // keep 16B align

    hipMemsetAsync(cnt, 0, NBKT * sizeof(int), stream);

    const int nbc = (npts + CNT_PTS - 1) / CNT_PTS;
    const int nbs = (npts + SC_PTS - 1) / SC_PTS;
    hipLaunchKernelGGL(count_kernel,   dim3(nbc), dim3(CNT_TPB), 0, stream, points, npts, cnt);
    hipLaunchKernelGGL(scan_kernel,    dim3(1),   dim3(NBKT),    0, stream, cnt, cursor);
    hipLaunchKernelGGL(scatter_kernel, dim3(nbs), dim3(SC_TPB),  0, stream, points, npts, cursor, recs);

    const int grid = (npts + PPB - 1) / PPB;
    hipLaunchKernelGGL(trilerp_kernel, dim3(grid), dim3(TPB), 0, stream,
                       data, links, recs, out, npts);
}